// Round 2
// baseline (547.375 us; speedup 1.0000x reference)
//
#include <hip/hip_runtime.h>

// S4 layer: y = C * scan(a_bar, dt*B*u) + u*D
//   prep_pow: dt = mean(exp(log_dt)); A_bar = I + dt*A; A_pow = A_bar^64 (6 LDS squarings)
//   gemm1:    bu[m][n] = dt * sum_k u[m][k] * B[n][k]     (MFMA bf16 3-term split)
//   scan<0>:  per-chunk local scan from zero -> chunk end states E
//   combine:  S_{j+1} = A_pow * S_j + E_j (sequential over 64 chunks, per batch)
//   scan<1>:  re-run recurrence with true initial states; writes xs packed bf16(hi,lo) in place
//   gemm2:    y[m][d] = sum_n xs[m][n]*C[d][n] + u[m][d]*D[d]  (MFMA bf16 3-term split)

#define DM   1024
#define DS   64
#define NB   16
#define LL   4096
#define LC   64
#define NCH  (LL / LC)     // 64
#define MTOT (NB * LL)     // 65536

// workspace layout in floats
#define WS_ABAR 64
#define WS_APOW (WS_ABAR + 4096)          // 4160
#define WS_E    (WS_APOW + 4096)          // 8256
#define WS_S    (WS_E + NB * NCH * DS)    // 73792
#define WS_BU   (WS_S + NB * NCH * DS)    // 139328
// total = 139328 + 65536*64 floats ~= 17.3 MB

typedef __attribute__((ext_vector_type(4))) float f32x4;
typedef __attribute__((ext_vector_type(8))) short bf16x8;

__device__ inline unsigned short bf16_rne(float f) {
    unsigned u = __builtin_bit_cast(unsigned, f);
    u += 0x7FFFu + ((u >> 16) & 1u);
    return (unsigned short)(u >> 16);
}
__device__ inline float bf16f(unsigned short h) {
    unsigned u = ((unsigned)h) << 16;
    return __builtin_bit_cast(float, u);
}

// ---------------- prep + A_bar^64 in one block ----------------
__global__ __launch_bounds__(256) void k_prep_pow(const float* __restrict__ A,
                                                  const float* __restrict__ log_dt,
                                                  float* __restrict__ ws) {
    __shared__ float red[256];
    __shared__ float m0[64][65], m1[64][65];
    int tid = threadIdx.x;
    float s = 0.f;
    for (int i = tid; i < DM; i += 256) s += expf(log_dt[i]);
    red[tid] = s;
    __syncthreads();
    for (int off = 128; off > 0; off >>= 1) {
        if (tid < off) red[tid] += red[tid + off];
        __syncthreads();
    }
    float dt = red[0] * (1.f / (float)DM);
    if (tid == 0) ws[0] = dt;
    for (int idx = tid; idx < 4096; idx += 256) {
        int n = idx >> 6, m = idx & 63;
        float v = dt * A[idx] + ((n == m) ? 1.f : 0.f);
        m0[n][m] = v;
        ws[WS_ABAR + idx] = v;
    }
    __syncthreads();
#pragma unroll 1
    for (int sq = 0; sq < 6; ++sq) {
        float (*src)[65] = (sq & 1) ? m1 : m0;
        float (*dst)[65] = (sq & 1) ? m0 : m1;
#pragma unroll
        for (int rep = 0; rep < 16; ++rep) {
            int idx = rep * 256 + tid;
            int n = idx >> 6, m = idx & 63;   // n wave-uniform
            float a0 = 0.f, a1 = 0.f, a2 = 0.f, a3 = 0.f;
#pragma unroll
            for (int k = 0; k < 64; k += 4) {
                a0 = fmaf(src[n][k + 0], src[k + 0][m], a0);
                a1 = fmaf(src[n][k + 1], src[k + 1][m], a1);
                a2 = fmaf(src[n][k + 2], src[k + 2][m], a2);
                a3 = fmaf(src[n][k + 3], src[k + 3][m], a3);
            }
            dst[n][m] = (a0 + a1) + (a2 + a3);
        }
        __syncthreads();
    }
    // result of 6th squaring landed in m0
    for (int idx = tid; idx < 4096; idx += 256)
        ws[WS_APOW + idx] = m0[idx >> 6][idx & 63];
}

// ---------------- GEMM1: bu = dt * u @ B^T  (M=65536,K=1024,N=64) ----------------
// 256 thr = 4 waves; M-tile 128 (wave owns 32 rows), N=64 full, K-step 64.
// LDS rows padded to 72 bf16 (144B) -> conflict-free ds_read_b128 fragments.
__global__ __launch_bounds__(256) void k_gemm1(const float* __restrict__ u,
                                               const float* __restrict__ Bm,
                                               const float* __restrict__ ws,
                                               float* __restrict__ bu) {
    __shared__ short a_hi[128][72], a_lo[128][72];   // 18432 B each
    __shared__ short b_hi[64][72],  b_lo[64][72];    // 9216 B each
    int tid = threadIdx.x;
    int m0 = blockIdx.x * 128;
    int wid = tid >> 6, lane = tid & 63;
    int lr = lane & 15, lg = lane >> 4;
    float dt = ws[0];

    f32x4 acc[2][4];
#pragma unroll
    for (int i = 0; i < 2; ++i)
#pragma unroll
        for (int j = 0; j < 4; ++j) acc[i][j] = (f32x4)(0.f);

    for (int kt = 0; kt < 16; ++kt) {
        int k0 = kt * 64;
#pragma unroll
        for (int rep = 0; rep < 8; ++rep) {            // stage u tile 128x64
            int idx = rep * 256 + tid;
            int r = idx >> 4, c4 = (idx & 15) << 2;
            float4 v = *reinterpret_cast<const float4*>(&u[(size_t)(m0 + r) * DM + k0 + c4]);
            ushort4 h, l;
            h.x = bf16_rne(v.x); l.x = bf16_rne(v.x - bf16f(h.x));
            h.y = bf16_rne(v.y); l.y = bf16_rne(v.y - bf16f(h.y));
            h.z = bf16_rne(v.z); l.z = bf16_rne(v.z - bf16f(h.z));
            h.w = bf16_rne(v.w); l.w = bf16_rne(v.w - bf16f(h.w));
            *reinterpret_cast<ushort4*>(&a_hi[r][c4]) = h;
            *reinterpret_cast<ushort4*>(&a_lo[r][c4]) = l;
        }
#pragma unroll
        for (int rep = 0; rep < 4; ++rep) {            // stage B tile 64x64 (as [n][k])
            int idx = rep * 256 + tid;
            int n = idx >> 4, k4 = (idx & 15) << 2;
            float4 v = *reinterpret_cast<const float4*>(&Bm[(size_t)n * DM + k0 + k4]);
            ushort4 h, l;
            h.x = bf16_rne(v.x); l.x = bf16_rne(v.x - bf16f(h.x));
            h.y = bf16_rne(v.y); l.y = bf16_rne(v.y - bf16f(h.y));
            h.z = bf16_rne(v.z); l.z = bf16_rne(v.z - bf16f(h.z));
            h.w = bf16_rne(v.w); l.w = bf16_rne(v.w - bf16f(h.w));
            *reinterpret_cast<ushort4*>(&b_hi[n][k4]) = h;
            *reinterpret_cast<ushort4*>(&b_lo[n][k4]) = l;
        }
        __syncthreads();
#pragma unroll
        for (int kf = 0; kf < 2; ++kf) {
            int kb = kf * 32 + lg * 8;
            bf16x8 ah[2], al[2];
#pragma unroll
            for (int mf = 0; mf < 2; ++mf) {
                ah[mf] = *reinterpret_cast<bf16x8*>(&a_hi[wid * 32 + mf * 16 + lr][kb]);
                al[mf] = *reinterpret_cast<bf16x8*>(&a_lo[wid * 32 + mf * 16 + lr][kb]);
            }
#pragma unroll
            for (int nf = 0; nf < 4; ++nf) {
                bf16x8 bh = *reinterpret_cast<bf16x8*>(&b_hi[nf * 16 + lr][kb]);
                bf16x8 bl = *reinterpret_cast<bf16x8*>(&b_lo[nf * 16 + lr][kb]);
#pragma unroll
                for (int mf = 0; mf < 2; ++mf) {
                    acc[mf][nf] = __builtin_amdgcn_mfma_f32_16x16x32_bf16(ah[mf], bh, acc[mf][nf], 0, 0, 0);
                    acc[mf][nf] = __builtin_amdgcn_mfma_f32_16x16x32_bf16(ah[mf], bl, acc[mf][nf], 0, 0, 0);
                    acc[mf][nf] = __builtin_amdgcn_mfma_f32_16x16x32_bf16(al[mf], bh, acc[mf][nf], 0, 0, 0);
                }
            }
        }
        __syncthreads();
    }
    // epilogue: D frag row=(lg*4+q), col=lr
#pragma unroll
    for (int mf = 0; mf < 2; ++mf)
#pragma unroll
        for (int nf = 0; nf < 4; ++nf)
#pragma unroll
            for (int q = 0; q < 4; ++q) {
                size_t row = (size_t)(m0 + wid * 32 + mf * 16 + lg * 4 + q);
                bu[row * DS + nf * 16 + lr] = dt * acc[mf][nf][q];
            }
}

// ---------------- chunked scan ----------------
// One wave per (batch, chunk). Lane n holds x[n] and row n of A_bar in 64 VGPRs.
// PASS 0: zero init -> write chunk end state E. PASS 1: from S_j, write xs packed bf16.
template <int PASS>
__global__ __launch_bounds__(256) void k_scan(float* __restrict__ ws) {
    const float* Abar = ws + WS_ABAR;
    float* bu = ws + WS_BU;
    int tid = threadIdx.x;
    int w = tid >> 6, lane = tid & 63;
    int task = blockIdx.x * 4 + w;          // task = b*NCH + j
    int b = task >> 6;
    int j = task & 63;
    __shared__ float xbuf[4][64];

    float a_row[64];
#pragma unroll
    for (int mg = 0; mg < 16; ++mg) {
        float4 v = *reinterpret_cast<const float4*>(&Abar[lane * 64 + mg * 4]);
        a_row[mg * 4 + 0] = v.x; a_row[mg * 4 + 1] = v.y;
        a_row[mg * 4 + 2] = v.z; a_row[mg * 4 + 3] = v.w;
    }
    float x;
    if (PASS == 0) x = 0.f;
    else           x = ws[WS_S + (size_t)task * DS + lane];

    float* bub = bu + ((size_t)b * LL + (size_t)j * LC) * DS;
    unsigned* bup = reinterpret_cast<unsigned*>(bub);
    float buv = bub[lane];
    for (int t = 0; t < LC; ++t) {
        float bunext = 0.f;
        if (t + 1 < LC) bunext = bub[(t + 1) * DS + lane];  // prefetch
        xbuf[w][lane] = x;
        asm volatile("" ::: "memory");
        float part[4];
#pragma unroll
        for (int g = 0; g < 4; ++g) {
            float acc = (g == 0) ? buv : 0.f;
#pragma unroll
            for (int q = 0; q < 4; ++q) {
                float4 xm = *reinterpret_cast<float4*>(&xbuf[w][g * 16 + q * 4]);
                acc = fmaf(a_row[g * 16 + q * 4 + 0], xm.x, acc);
                acc = fmaf(a_row[g * 16 + q * 4 + 1], xm.y, acc);
                acc = fmaf(a_row[g * 16 + q * 4 + 2], xm.z, acc);
                acc = fmaf(a_row[g * 16 + q * 4 + 3], xm.w, acc);
            }
            part[g] = acc;
        }
        asm volatile("" ::: "memory");
        x = (part[0] + part[1]) + (part[2] + part[3]);
        if (PASS == 1) {
            unsigned short h = bf16_rne(x);
            unsigned short l = bf16_rne(x - bf16f(h));
            bup[t * DS + lane] = (unsigned)h | ((unsigned)l << 16);
        }
        buv = bunext;
    }
    if (PASS == 0) ws[WS_E + (size_t)task * DS + lane] = x;
}

// ---------------- sequential chunk-boundary propagation ----------------
__global__ __launch_bounds__(64) void k_combine(float* __restrict__ ws) {
    const float* Apow = ws + WS_APOW;
    int b = blockIdx.x;
    int lane = threadIdx.x;
    __shared__ float xbuf[64];
    float p_row[64];
#pragma unroll
    for (int mg = 0; mg < 16; ++mg) {
        float4 v = *reinterpret_cast<const float4*>(&Apow[lane * 64 + mg * 4]);
        p_row[mg * 4 + 0] = v.x; p_row[mg * 4 + 1] = v.y;
        p_row[mg * 4 + 2] = v.z; p_row[mg * 4 + 3] = v.w;
    }
    float x = 0.f;
    for (int jj = 0; jj < NCH; ++jj) {
        size_t task = (size_t)b * NCH + jj;
        ws[WS_S + task * DS + lane] = x;
        float e = ws[WS_E + task * DS + lane];
        xbuf[lane] = x;
        asm volatile("" ::: "memory");
        float part[4];
#pragma unroll
        for (int g = 0; g < 4; ++g) {
            float acc = (g == 0) ? e : 0.f;
#pragma unroll
            for (int q = 0; q < 4; ++q) {
                float4 xm = *reinterpret_cast<float4*>(&xbuf[g * 16 + q * 4]);
                acc = fmaf(p_row[g * 16 + q * 4 + 0], xm.x, acc);
                acc = fmaf(p_row[g * 16 + q * 4 + 1], xm.y, acc);
                acc = fmaf(p_row[g * 16 + q * 4 + 2], xm.z, acc);
                acc = fmaf(p_row[g * 16 + q * 4 + 3], xm.w, acc);
            }
            part[g] = acc;
        }
        asm volatile("" ::: "memory");
        x = (part[0] + part[1]) + (part[2] + part[3]);
    }
}

// ---------------- GEMM2: y = xs @ C^T + u*D  (M=65536,K=64,N=1024) ----------------
// 256 thr = 4 waves; M-tile 128, N-tile 64, K=64 single stage. xs arrives packed bf16.
__global__ __launch_bounds__(256) void k_gemm2(const float* __restrict__ u,
                                               const float* __restrict__ C,
                                               const float* __restrict__ Dv,
                                               const float* __restrict__ ws,
                                               float* __restrict__ y) {
    __shared__ short a_hi[128][72], a_lo[128][72];   // also reused as f32 out tile
    __shared__ short c_hi[64][72],  c_lo[64][72];
    const unsigned* bup = reinterpret_cast<const unsigned*>(ws + WS_BU);
    int tid = threadIdx.x;
    int m0 = blockIdx.x * 128;
    int d0 = blockIdx.y * 64;
    int wid = tid >> 6, lane = tid & 63;
    int lr = lane & 15, lg = lane >> 4;

#pragma unroll
    for (int rep = 0; rep < 8; ++rep) {            // stage xs tile 128x64 (packed hi|lo)
        int idx = rep * 256 + tid;
        int r = idx >> 4, c4 = (idx & 15) << 2;
        uint4 v = *reinterpret_cast<const uint4*>(&bup[(size_t)(m0 + r) * DS + c4]);
        ushort4 h, l;
        h.x = (unsigned short)(v.x & 0xFFFF); l.x = (unsigned short)(v.x >> 16);
        h.y = (unsigned short)(v.y & 0xFFFF); l.y = (unsigned short)(v.y >> 16);
        h.z = (unsigned short)(v.z & 0xFFFF); l.z = (unsigned short)(v.z >> 16);
        h.w = (unsigned short)(v.w & 0xFFFF); l.w = (unsigned short)(v.w >> 16);
        *reinterpret_cast<ushort4*>(&a_hi[r][c4]) = h;
        *reinterpret_cast<ushort4*>(&a_lo[r][c4]) = l;
    }
#pragma unroll
    for (int rep = 0; rep < 4; ++rep) {            // stage C^T tile: ct[d_local][k=n]
        int idx = rep * 256 + tid;
        int dl = idx >> 4, n4 = (idx & 15) << 2;
        float4 v = *reinterpret_cast<const float4*>(&C[(size_t)(d0 + dl) * DS + n4]);
        ushort4 h, l;
        h.x = bf16_rne(v.x); l.x = bf16_rne(v.x - bf16f(h.x));
        h.y = bf16_rne(v.y); l.y = bf16_rne(v.y - bf16f(h.y));
        h.z = bf16_rne(v.z); l.z = bf16_rne(v.z - bf16f(h.z));
        h.w = bf16_rne(v.w); l.w = bf16_rne(v.w - bf16f(h.w));
        *reinterpret_cast<ushort4*>(&c_hi[dl][n4]) = h;
        *reinterpret_cast<ushort4*>(&c_lo[dl][n4]) = l;
    }
    __syncthreads();

    f32x4 acc[2][4];
#pragma unroll
    for (int i = 0; i < 2; ++i)
#pragma unroll
        for (int j = 0; j < 4; ++j) acc[i][j] = (f32x4)(0.f);

#pragma unroll
    for (int kf = 0; kf < 2; ++kf) {
        int kb = kf * 32 + lg * 8;
        bf16x8 ah[2], al[2];
#pragma unroll
        for (int mf = 0; mf < 2; ++mf) {
            ah[mf] = *reinterpret_cast<bf16x8*>(&a_hi[wid * 32 + mf * 16 + lr][kb]);
            al[mf] = *reinterpret_cast<bf16x8*>(&a_lo[wid * 32 + mf * 16 + lr][kb]);
        }
#pragma unroll
        for (int nf = 0; nf < 4; ++nf) {
            bf16x8 bh = *reinterpret_cast<bf16x8*>(&c_hi[nf * 16 + lr][kb]);
            bf16x8 bl = *reinterpret_cast<bf16x8*>(&c_lo[nf * 16 + lr][kb]);
#pragma unroll
            for (int mf = 0; mf < 2; ++mf) {
                acc[mf][nf] = __builtin_amdgcn_mfma_f32_16x16x32_bf16(ah[mf], bh, acc[mf][nf], 0, 0, 0);
                acc[mf][nf] = __builtin_amdgcn_mfma_f32_16x16x32_bf16(ah[mf], bl, acc[mf][nf], 0, 0, 0);
                acc[mf][nf] = __builtin_amdgcn_mfma_f32_16x16x32_bf16(al[mf], bh, acc[mf][nf], 0, 0, 0);
            }
        }
    }
    __syncthreads();   // frag reads done; reuse a_hi/a_lo region as f32 [128][68]
    float* out_lds = reinterpret_cast<float*>(&a_hi[0][0]);
#pragma unroll
    for (int mf = 0; mf < 2; ++mf)
#pragma unroll
        for (int nf = 0; nf < 4; ++nf)
#pragma unroll
            for (int q = 0; q < 4; ++q)
                out_lds[(wid * 32 + mf * 16 + lg * 4 + q) * 68 + nf * 16 + lr] = acc[mf][nf][q];
    __syncthreads();
#pragma unroll
    for (int rep = 0; rep < 8; ++rep) {            // coalesced float4 epilogue
        int idx = rep * 256 + tid;
        int r = idx >> 4, c4 = (idx & 15) << 2;
        float4 a = *reinterpret_cast<float4*>(&out_lds[r * 68 + c4]);
        size_t row = (size_t)(m0 + r);
        int c = d0 + c4;
        float4 uv = *reinterpret_cast<const float4*>(&u[row * DM + c]);
        float4 dv = *reinterpret_cast<const float4*>(&Dv[c]);
        float4 o;
        o.x = a.x + uv.x * dv.x;
        o.y = a.y + uv.y * dv.y;
        o.z = a.z + uv.z * dv.z;
        o.w = a.w + uv.w * dv.w;
        *reinterpret_cast<float4*>(&y[row * DM + c]) = o;
    }
}

extern "C" void kernel_launch(void* const* d_in, const int* in_sizes, int n_in,
                              void* d_out, int out_size, void* d_ws, size_t ws_size,
                              hipStream_t stream) {
    (void)in_sizes; (void)n_in; (void)out_size; (void)ws_size;
    const float* u      = (const float*)d_in[0];
    const float* A      = (const float*)d_in[1];
    const float* Bm     = (const float*)d_in[2];
    const float* C      = (const float*)d_in[3];
    const float* Dv     = (const float*)d_in[4];
    const float* log_dt = (const float*)d_in[5];
    float* y  = (float*)d_out;
    float* ws = (float*)d_ws;
    float* bu = ws + WS_BU;

    k_prep_pow<<<dim3(1), dim3(256), 0, stream>>>(A, log_dt, ws);
    k_gemm1<<<dim3(MTOT / 128), dim3(256), 0, stream>>>(u, Bm, ws, bu);
    k_scan<0><<<dim3(NB * NCH / 4), dim3(256), 0, stream>>>(ws);
    k_combine<<<dim3(NB), dim3(64), 0, stream>>>(ws);
    k_scan<1><<<dim3(NB * NCH / 4), dim3(256), 0, stream>>>(ws);
    k_gemm2<<<dim3(MTOT / 128, DM / 64), dim3(256), 0, stream>>>(u, C, Dv, ws, y);
}

// Round 3
// 423.705 us; speedup vs baseline: 1.2919x; 1.2919x over previous
//
#include <hip/hip_runtime.h>

// S4 layer: y = C * scan(a_bar, dt*B*u) + u*D
//   prep:     dt = mean(exp(log_dt)); A_bar = I + dt*A
//   matsq x6: A_pow = A_bar^64 (16-block kernels, ping-pong)
//   gemm1:    bu[m][n] = dt * sum_k u[m][k] * B[n][k]     (MFMA bf16 3-term split)
//   scan<0>:  per-chunk local scan from zero -> chunk end states E  (2 tasks/wave)
//   combine:  S_{j+1} = A_pow * S_j + E_j (sequential over 64 chunks, per batch)
//   scan<1>:  re-run recurrence with true initial states; writes xs packed bf16(hi,lo)
//   gemm2:    y[m][d] = sum_n xs[m][n]*C[d][n] + u[m][d]*D[d]  (MFMA bf16 3-term split)

#define DM   1024
#define DS   64
#define NB   16
#define LL   4096
#define LC   64
#define NCH  (LL / LC)     // 64
#define MTOT (NB * LL)     // 65536
#define NTASK (NB * NCH)   // 1024

// workspace layout in floats
#define WS_ABAR 64
#define WS_APOW (WS_ABAR + 4096)          // 4160
#define WS_TMP  (WS_APOW + 4096)          // 8256
#define WS_E    (WS_TMP + 4096)           // 12352
#define WS_S    (WS_E + NTASK * DS)       // 77888
#define WS_BU   (WS_S + NTASK * DS)       // 143424

typedef __attribute__((ext_vector_type(4))) float f32x4;
typedef __attribute__((ext_vector_type(8))) short bf16x8;

__device__ inline unsigned short bf16_rne(float f) {
    unsigned u = __builtin_bit_cast(unsigned, f);
    u += 0x7FFFu + ((u >> 16) & 1u);
    return (unsigned short)(u >> 16);
}
__device__ inline float bf16f(unsigned short h) {
    unsigned u = ((unsigned)h) << 16;
    return __builtin_bit_cast(float, u);
}

// ---------------- prep: dt + A_bar ----------------
__global__ __launch_bounds__(256) void k_prep(const float* __restrict__ A,
                                              const float* __restrict__ log_dt,
                                              float* __restrict__ ws) {
    __shared__ float red[256];
    int tid = threadIdx.x;
    float s = 0.f;
    for (int i = tid; i < DM; i += 256) s += expf(log_dt[i]);
    red[tid] = s;
    __syncthreads();
    for (int off = 128; off > 0; off >>= 1) {
        if (tid < off) red[tid] += red[tid + off];
        __syncthreads();
    }
    float dt = red[0] * (1.f / (float)DM);
    if (tid == 0) ws[0] = dt;
    for (int idx = tid; idx < 4096; idx += 256) {
        int n = idx >> 6, m = idx & 63;
        ws[WS_ABAR + idx] = dt * A[idx] + ((n == m) ? 1.f : 0.f);
    }
}

// dst = src*src for a 64x64 matrix. grid=16 blocks x 256 thr (1 output/thread).
__global__ __launch_bounds__(256) void k_matsq(const float* __restrict__ src,
                                               float* __restrict__ dst) {
    __shared__ float s[64][65];
    int tid = threadIdx.x;
#pragma unroll
    for (int rep = 0; rep < 16; ++rep) {
        int idx = rep * 256 + tid;
        s[idx >> 6][idx & 63] = src[idx];
    }
    __syncthreads();
    int n = (blockIdx.x << 2) + (tid >> 6);  // wave-uniform row
    int m = tid & 63;
    float a0 = 0.f, a1 = 0.f, a2 = 0.f, a3 = 0.f;
#pragma unroll
    for (int k = 0; k < 64; k += 4) {
        a0 = fmaf(s[n][k + 0], s[k + 0][m], a0);
        a1 = fmaf(s[n][k + 1], s[k + 1][m], a1);
        a2 = fmaf(s[n][k + 2], s[k + 2][m], a2);
        a3 = fmaf(s[n][k + 3], s[k + 3][m], a3);
    }
    dst[(n << 6) + m] = (a0 + a1) + (a2 + a3);
}

// ---------------- GEMM1: bu = dt * u @ B^T  (M=65536,K=1024,N=64) ----------------
__global__ __launch_bounds__(256) void k_gemm1(const float* __restrict__ u,
                                               const float* __restrict__ Bm,
                                               const float* __restrict__ ws,
                                               float* __restrict__ bu) {
    __shared__ short a_hi[128][72], a_lo[128][72];
    __shared__ short b_hi[64][72],  b_lo[64][72];
    int tid = threadIdx.x;
    int m0 = blockIdx.x * 128;
    int wid = tid >> 6, lane = tid & 63;
    int lr = lane & 15, lg = lane >> 4;
    float dt = ws[0];

    f32x4 acc[2][4];
#pragma unroll
    for (int i = 0; i < 2; ++i)
#pragma unroll
        for (int j = 0; j < 4; ++j) acc[i][j] = (f32x4)(0.f);

    for (int kt = 0; kt < 16; ++kt) {
        int k0 = kt * 64;
#pragma unroll
        for (int rep = 0; rep < 8; ++rep) {            // stage u tile 128x64
            int idx = rep * 256 + tid;
            int r = idx >> 4, c4 = (idx & 15) << 2;
            float4 v = *reinterpret_cast<const float4*>(&u[(size_t)(m0 + r) * DM + k0 + c4]);
            ushort4 h, l;
            h.x = bf16_rne(v.x); l.x = bf16_rne(v.x - bf16f(h.x));
            h.y = bf16_rne(v.y); l.y = bf16_rne(v.y - bf16f(h.y));
            h.z = bf16_rne(v.z); l.z = bf16_rne(v.z - bf16f(h.z));
            h.w = bf16_rne(v.w); l.w = bf16_rne(v.w - bf16f(h.w));
            *reinterpret_cast<ushort4*>(&a_hi[r][c4]) = h;
            *reinterpret_cast<ushort4*>(&a_lo[r][c4]) = l;
        }
#pragma unroll
        for (int rep = 0; rep < 4; ++rep) {            // stage B tile 64x64 (as [n][k])
            int idx = rep * 256 + tid;
            int n = idx >> 4, k4 = (idx & 15) << 2;
            float4 v = *reinterpret_cast<const float4*>(&Bm[(size_t)n * DM + k0 + k4]);
            ushort4 h, l;
            h.x = bf16_rne(v.x); l.x = bf16_rne(v.x - bf16f(h.x));
            h.y = bf16_rne(v.y); l.y = bf16_rne(v.y - bf16f(h.y));
            h.z = bf16_rne(v.z); l.z = bf16_rne(v.z - bf16f(h.z));
            h.w = bf16_rne(v.w); l.w = bf16_rne(v.w - bf16f(h.w));
            *reinterpret_cast<ushort4*>(&b_hi[n][k4]) = h;
            *reinterpret_cast<ushort4*>(&b_lo[n][k4]) = l;
        }
        __syncthreads();
#pragma unroll
        for (int kf = 0; kf < 2; ++kf) {
            int kb = kf * 32 + lg * 8;
            bf16x8 ah[2], al[2];
#pragma unroll
            for (int mf = 0; mf < 2; ++mf) {
                ah[mf] = *reinterpret_cast<bf16x8*>(&a_hi[wid * 32 + mf * 16 + lr][kb]);
                al[mf] = *reinterpret_cast<bf16x8*>(&a_lo[wid * 32 + mf * 16 + lr][kb]);
            }
#pragma unroll
            for (int nf = 0; nf < 4; ++nf) {
                bf16x8 bh = *reinterpret_cast<bf16x8*>(&b_hi[nf * 16 + lr][kb]);
                bf16x8 bl = *reinterpret_cast<bf16x8*>(&b_lo[nf * 16 + lr][kb]);
#pragma unroll
                for (int mf = 0; mf < 2; ++mf) {
                    acc[mf][nf] = __builtin_amdgcn_mfma_f32_16x16x32_bf16(ah[mf], bh, acc[mf][nf], 0, 0, 0);
                    acc[mf][nf] = __builtin_amdgcn_mfma_f32_16x16x32_bf16(ah[mf], bl, acc[mf][nf], 0, 0, 0);
                    acc[mf][nf] = __builtin_amdgcn_mfma_f32_16x16x32_bf16(al[mf], bh, acc[mf][nf], 0, 0, 0);
                }
            }
        }
        __syncthreads();
    }
#pragma unroll
    for (int mf = 0; mf < 2; ++mf)
#pragma unroll
        for (int nf = 0; nf < 4; ++nf)
#pragma unroll
            for (int q = 0; q < 4; ++q) {
                size_t row = (size_t)(m0 + wid * 32 + mf * 16 + lg * 4 + q);
                bu[row * DS + nf * 16 + lr] = dt * acc[mf][nf][q];
            }
}

// ---------------- chunked scan: 2 independent tasks per wave ----------------
// Lane n holds x[n] and row n of A_bar (64 VGPRs). LDS same-address float4 reads
// broadcast the state vector. Two interleaved recurrences hide LDS/FMA latency.
template <int PASS>
__global__ __launch_bounds__(256) void k_scan(float* __restrict__ ws) {
    const float* Abar = ws + WS_ABAR;
    float* bu = ws + WS_BU;
    int tid = threadIdx.x;
    int w = tid >> 6, lane = tid & 63;
    int t0 = blockIdx.x * 4 + w;            // 0..511
    int t1 = t0 + 512;                      // 512..1023
    __shared__ float xbuf[4][2][64];

    float a_row[64];
#pragma unroll
    for (int mg = 0; mg < 16; ++mg) {
        float4 v = *reinterpret_cast<const float4*>(&Abar[lane * 64 + mg * 4]);
        a_row[mg * 4 + 0] = v.x; a_row[mg * 4 + 1] = v.y;
        a_row[mg * 4 + 2] = v.z; a_row[mg * 4 + 3] = v.w;
    }
    float x0, x1;
    if (PASS == 0) { x0 = 0.f; x1 = 0.f; }
    else {
        x0 = ws[WS_S + (size_t)t0 * DS + lane];
        x1 = ws[WS_S + (size_t)t1 * DS + lane];
    }
    float* bub0 = bu + ((size_t)(t0 >> 6) * LL + (size_t)(t0 & 63) * LC) * DS;
    float* bub1 = bu + ((size_t)(t1 >> 6) * LL + (size_t)(t1 & 63) * LC) * DS;
    unsigned* bup0 = reinterpret_cast<unsigned*>(bub0);
    unsigned* bup1 = reinterpret_cast<unsigned*>(bub1);
    float v0 = bub0[lane], v1 = bub1[lane];
    for (int t = 0; t < LC; ++t) {
        float n0 = 0.f, n1 = 0.f;
        if (t + 1 < LC) {                    // prefetch next inputs
            n0 = bub0[(t + 1) * DS + lane];
            n1 = bub1[(t + 1) * DS + lane];
        }
        xbuf[w][0][lane] = x0;
        xbuf[w][1][lane] = x1;
        asm volatile("" ::: "memory");
        float p0[4], p1[4];
#pragma unroll
        for (int g = 0; g < 4; ++g) {
            float acc0 = (g == 0) ? v0 : 0.f;
            float acc1 = (g == 0) ? v1 : 0.f;
#pragma unroll
            for (int q = 0; q < 4; ++q) {
                float4 m0v = *reinterpret_cast<float4*>(&xbuf[w][0][g * 16 + q * 4]);
                float4 m1v = *reinterpret_cast<float4*>(&xbuf[w][1][g * 16 + q * 4]);
                float c0 = a_row[g * 16 + q * 4 + 0], c1 = a_row[g * 16 + q * 4 + 1];
                float c2 = a_row[g * 16 + q * 4 + 2], c3 = a_row[g * 16 + q * 4 + 3];
                acc0 = fmaf(c0, m0v.x, acc0); acc1 = fmaf(c0, m1v.x, acc1);
                acc0 = fmaf(c1, m0v.y, acc0); acc1 = fmaf(c1, m1v.y, acc1);
                acc0 = fmaf(c2, m0v.z, acc0); acc1 = fmaf(c2, m1v.z, acc1);
                acc0 = fmaf(c3, m0v.w, acc0); acc1 = fmaf(c3, m1v.w, acc1);
            }
            p0[g] = acc0; p1[g] = acc1;
        }
        asm volatile("" ::: "memory");
        x0 = (p0[0] + p0[1]) + (p0[2] + p0[3]);
        x1 = (p1[0] + p1[1]) + (p1[2] + p1[3]);
        if (PASS == 1) {
            unsigned short h0 = bf16_rne(x0);
            unsigned short l0 = bf16_rne(x0 - bf16f(h0));
            unsigned short h1 = bf16_rne(x1);
            unsigned short l1 = bf16_rne(x1 - bf16f(h1));
            bup0[t * DS + lane] = (unsigned)h0 | ((unsigned)l0 << 16);
            bup1[t * DS + lane] = (unsigned)h1 | ((unsigned)l1 << 16);
        }
        v0 = n0; v1 = n1;
    }
    if (PASS == 0) {
        ws[WS_E + (size_t)t0 * DS + lane] = x0;
        ws[WS_E + (size_t)t1 * DS + lane] = x1;
    }
}

// ---------------- sequential chunk-boundary propagation ----------------
__global__ __launch_bounds__(64) void k_combine(float* __restrict__ ws) {
    const float* Apow = ws + WS_APOW;
    int b = blockIdx.x;
    int lane = threadIdx.x;
    __shared__ float xbuf[64];
    float p_row[64];
#pragma unroll
    for (int mg = 0; mg < 16; ++mg) {
        float4 v = *reinterpret_cast<const float4*>(&Apow[lane * 64 + mg * 4]);
        p_row[mg * 4 + 0] = v.x; p_row[mg * 4 + 1] = v.y;
        p_row[mg * 4 + 2] = v.z; p_row[mg * 4 + 3] = v.w;
    }
    float x = 0.f;
    for (int jj = 0; jj < NCH; ++jj) {
        size_t task = (size_t)b * NCH + jj;
        ws[WS_S + task * DS + lane] = x;
        float e = ws[WS_E + task * DS + lane];
        xbuf[lane] = x;
        asm volatile("" ::: "memory");
        float part[4];
#pragma unroll
        for (int g = 0; g < 4; ++g) {
            float acc = (g == 0) ? e : 0.f;
#pragma unroll
            for (int q = 0; q < 4; ++q) {
                float4 xm = *reinterpret_cast<float4*>(&xbuf[g * 16 + q * 4]);
                acc = fmaf(p_row[g * 16 + q * 4 + 0], xm.x, acc);
                acc = fmaf(p_row[g * 16 + q * 4 + 1], xm.y, acc);
                acc = fmaf(p_row[g * 16 + q * 4 + 2], xm.z, acc);
                acc = fmaf(p_row[g * 16 + q * 4 + 3], xm.w, acc);
            }
            part[g] = acc;
        }
        asm volatile("" ::: "memory");
        x = (part[0] + part[1]) + (part[2] + part[3]);
    }
}

// ---------------- GEMM2: y = xs @ C^T + u*D  (M=65536,K=64,N=1024) ----------------
// M-tile 128, N-tile 128, K=64 single stage. xs arrives packed bf16(hi,lo).
__global__ __launch_bounds__(256) void k_gemm2(const float* __restrict__ u,
                                               const float* __restrict__ C,
                                               const float* __restrict__ Dv,
                                               const float* __restrict__ ws,
                                               float* __restrict__ y) {
    __shared__ __align__(16) char smem[4 * 128 * 72 * 2];   // 73728 B
    short (*a_hi)[72] = (short(*)[72])(smem);
    short (*a_lo)[72] = (short(*)[72])(smem + 18432);
    short (*c_hi)[72] = (short(*)[72])(smem + 36864);
    short (*c_lo)[72] = (short(*)[72])(smem + 55296);
    float (*out_lds)[132] = (float(*)[132])(smem);          // 67584 B, reused

    const unsigned* bup = reinterpret_cast<const unsigned*>(ws + WS_BU);
    int tid = threadIdx.x;
    int m0 = blockIdx.x * 128;
    int d0 = blockIdx.y * 128;
    int wid = tid >> 6, lane = tid & 63;
    int lr = lane & 15, lg = lane >> 4;

#pragma unroll
    for (int rep = 0; rep < 8; ++rep) {            // stage xs tile 128x64 (packed hi|lo)
        int idx = rep * 256 + tid;
        int r = idx >> 4, c4 = (idx & 15) << 2;
        uint4 v = *reinterpret_cast<const uint4*>(&bup[(size_t)(m0 + r) * DS + c4]);
        ushort4 h, l;
        h.x = (unsigned short)(v.x & 0xFFFF); l.x = (unsigned short)(v.x >> 16);
        h.y = (unsigned short)(v.y & 0xFFFF); l.y = (unsigned short)(v.y >> 16);
        h.z = (unsigned short)(v.z & 0xFFFF); l.z = (unsigned short)(v.z >> 16);
        h.w = (unsigned short)(v.w & 0xFFFF); l.w = (unsigned short)(v.w >> 16);
        *reinterpret_cast<ushort4*>(&a_hi[r][c4]) = h;
        *reinterpret_cast<ushort4*>(&a_lo[r][c4]) = l;
    }
#pragma unroll
    for (int rep = 0; rep < 8; ++rep) {            // stage C^T tile: ct[d_local][n]
        int idx = rep * 256 + tid;
        int dl = idx >> 4, n4 = (idx & 15) << 2;
        float4 v = *reinterpret_cast<const float4*>(&C[(size_t)(d0 + dl) * DS + n4]);
        ushort4 h, l;
        h.x = bf16_rne(v.x); l.x = bf16_rne(v.x - bf16f(h.x));
        h.y = bf16_rne(v.y); l.y = bf16_rne(v.y - bf16f(h.y));
        h.z = bf16_rne(v.z); l.z = bf16_rne(v.z - bf16f(h.z));
        h.w = bf16_rne(v.w); l.w = bf16_rne(v.w - bf16f(h.w));
        *reinterpret_cast<ushort4*>(&c_hi[dl][n4]) = h;
        *reinterpret_cast<ushort4*>(&c_lo[dl][n4]) = l;
    }
    __syncthreads();

    f32x4 acc[2][8];
#pragma unroll
    for (int i = 0; i < 2; ++i)
#pragma unroll
        for (int j = 0; j < 8; ++j) acc[i][j] = (f32x4)(0.f);

#pragma unroll
    for (int kf = 0; kf < 2; ++kf) {
        int kb = kf * 32 + lg * 8;
        bf16x8 ah[2], al[2];
#pragma unroll
        for (int mf = 0; mf < 2; ++mf) {
            ah[mf] = *reinterpret_cast<bf16x8*>(&a_hi[wid * 32 + mf * 16 + lr][kb]);
            al[mf] = *reinterpret_cast<bf16x8*>(&a_lo[wid * 32 + mf * 16 + lr][kb]);
        }
#pragma unroll
        for (int nf = 0; nf < 8; ++nf) {
            bf16x8 bh = *reinterpret_cast<bf16x8*>(&c_hi[nf * 16 + lr][kb]);
            bf16x8 bl = *reinterpret_cast<bf16x8*>(&c_lo[nf * 16 + lr][kb]);
#pragma unroll
            for (int mf = 0; mf < 2; ++mf) {
                acc[mf][nf] = __builtin_amdgcn_mfma_f32_16x16x32_bf16(ah[mf], bh, acc[mf][nf], 0, 0, 0);
                acc[mf][nf] = __builtin_amdgcn_mfma_f32_16x16x32_bf16(ah[mf], bl, acc[mf][nf], 0, 0, 0);
                acc[mf][nf] = __builtin_amdgcn_mfma_f32_16x16x32_bf16(al[mf], bh, acc[mf][nf], 0, 0, 0);
            }
        }
    }
    __syncthreads();   // frag reads done; reuse smem as f32 [128][132]
#pragma unroll
    for (int mf = 0; mf < 2; ++mf)
#pragma unroll
        for (int nf = 0; nf < 8; ++nf)
#pragma unroll
            for (int q = 0; q < 4; ++q)
                out_lds[wid * 32 + mf * 16 + lg * 4 + q][nf * 16 + lr] = acc[mf][nf][q];
    __syncthreads();
#pragma unroll
    for (int rep = 0; rep < 16; ++rep) {           // coalesced float4 epilogue
        int idx = rep * 256 + tid;
        int r = idx >> 5, c4 = (idx & 31) << 2;
        float4 a = *reinterpret_cast<float4*>(&out_lds[r][c4]);
        size_t row = (size_t)(m0 + r);
        int c = d0 + c4;
        float4 uv = *reinterpret_cast<const float4*>(&u[row * DM + c]);
        float4 dv = *reinterpret_cast<const float4*>(&Dv[c]);
        float4 o;
        o.x = a.x + uv.x * dv.x;
        o.y = a.y + uv.y * dv.y;
        o.z = a.z + uv.z * dv.z;
        o.w = a.w + uv.w * dv.w;
        *reinterpret_cast<float4*>(&y[row * DM + c]) = o;
    }
}

extern "C" void kernel_launch(void* const* d_in, const int* in_sizes, int n_in,
                              void* d_out, int out_size, void* d_ws, size_t ws_size,
                              hipStream_t stream) {
    (void)in_sizes; (void)n_in; (void)out_size; (void)ws_size;
    const float* u      = (const float*)d_in[0];
    const float* A      = (const float*)d_in[1];
    const float* Bm     = (const float*)d_in[2];
    const float* C      = (const float*)d_in[3];
    const float* Dv     = (const float*)d_in[4];
    const float* log_dt = (const float*)d_in[5];
    float* y  = (float*)d_out;
    float* ws = (float*)d_ws;
    float* bu = ws + WS_BU;

    k_prep<<<dim3(1), dim3(256), 0, stream>>>(A, log_dt, ws);
    k_matsq<<<dim3(16), dim3(256), 0, stream>>>(ws + WS_ABAR, ws + WS_TMP);   // A^2
    k_matsq<<<dim3(16), dim3(256), 0, stream>>>(ws + WS_TMP,  ws + WS_APOW);  // A^4
    k_matsq<<<dim3(16), dim3(256), 0, stream>>>(ws + WS_APOW, ws + WS_TMP);   // A^8
    k_matsq<<<dim3(16), dim3(256), 0, stream>>>(ws + WS_TMP,  ws + WS_APOW);  // A^16
    k_matsq<<<dim3(16), dim3(256), 0, stream>>>(ws + WS_APOW, ws + WS_TMP);   // A^32
    k_matsq<<<dim3(16), dim3(256), 0, stream>>>(ws + WS_TMP,  ws + WS_APOW);  // A^64

    k_gemm1<<<dim3(MTOT / 128), dim3(256), 0, stream>>>(u, Bm, ws, bu);
    k_scan<0><<<dim3(NTASK / 8), dim3(256), 0, stream>>>(ws);
    k_combine<<<dim3(NB), dim3(64), 0, stream>>>(ws);
    k_scan<1><<<dim3(NTASK / 8), dim3(256), 0, stream>>>(ws);
    k_gemm2<<<dim3(MTOT / 128, DM / 128), dim3(256), 0, stream>>>(u, C, Dv, ws, y);
}

// Round 5
// 396.230 us; speedup vs baseline: 1.3815x; 1.0693x over previous
//
#include <hip/hip_runtime.h>

// S4 layer: y = C * scan(a_bar, dt*B*u) + u*D
//   prep:     dt = mean(exp(log_dt)); A_bar = I + dt*A
//   matsq x6: A_pow = A_bar^64 (16-block kernels, ping-pong)
//   cvt x2:   B_hat = split_bf16(dt*B), C_hat = split_bf16(C)   (hi/lo pair)
//   gemm1:    bu[m][n] = sum_k u[m][k] * (dt*B)[n][k]   (MFMA bf16 3-term, reg-pipelined)
//   scan<0>:  per-chunk local scan from zero -> chunk end states E  (2 tasks/wave)
//   combine:  S_{j+1} = A_pow * S_j + E_j (sequential over 64 chunks, per batch)
//   scan<1>:  re-run recurrence with true initial states; writes xs packed bf16(hi,lo)
//   gemm2:    y[m][d] = sum_n xs[m][n]*C[d][n] + u[m][d]*D[d]  (MFMA bf16 3-term)

#define DM   1024
#define DS   64
#define NB   16
#define LL   4096
#define LC   64
#define NCH  (LL / LC)     // 64
#define MTOT (NB * LL)     // 65536
#define NTASK (NB * NCH)   // 1024

// workspace layout in floats
// NOTE: each split bf16 array holds 65536 ushorts = 131072 B = 32768 floats.
#define WS_ABAR 64
#define WS_APOW (WS_ABAR + 4096)          // 4160
#define WS_TMP  (WS_APOW + 4096)          // 8256
#define WS_E    (WS_TMP + 4096)           // 12352
#define WS_S    (WS_E + NTASK * DS)       // 77888
#define WS_BHI  143424
#define WS_BLO  (WS_BHI + 32768)          // 176192
#define WS_CHI  (WS_BLO + 32768)          // 208960
#define WS_CLO  (WS_CHI + 32768)          // 241728
#define WS_BU   (WS_CLO + 32768)          // 274496
// total = 274496 + 65536*64 floats ~= 17.9 MB

typedef __attribute__((ext_vector_type(4))) float f32x4;
typedef __attribute__((ext_vector_type(8))) short bf16x8;
typedef __attribute__((ext_vector_type(8))) unsigned short ushort8;

__device__ inline unsigned short bf16_rne(float f) {
    unsigned u = __builtin_bit_cast(unsigned, f);
    u += 0x7FFFu + ((u >> 16) & 1u);
    return (unsigned short)(u >> 16);
}
__device__ inline float bf16f(unsigned short h) {
    unsigned u = ((unsigned)h) << 16;
    return __builtin_bit_cast(float, u);
}

// ---------------- prep: dt + A_bar ----------------
__global__ __launch_bounds__(256) void k_prep(const float* __restrict__ A,
                                              const float* __restrict__ log_dt,
                                              float* __restrict__ ws) {
    __shared__ float red[256];
    int tid = threadIdx.x;
    float s = 0.f;
    for (int i = tid; i < DM; i += 256) s += expf(log_dt[i]);
    red[tid] = s;
    __syncthreads();
    for (int off = 128; off > 0; off >>= 1) {
        if (tid < off) red[tid] += red[tid + off];
        __syncthreads();
    }
    float dt = red[0] * (1.f / (float)DM);
    if (tid == 0) ws[0] = dt;
    for (int idx = tid; idx < 4096; idx += 256) {
        int n = idx >> 6, m = idx & 63;
        ws[WS_ABAR + idx] = dt * A[idx] + ((n == m) ? 1.f : 0.f);
    }
}

// dst = src*src for a 64x64 matrix. grid=16 blocks x 256 thr.
__global__ __launch_bounds__(256) void k_matsq(const float* __restrict__ src,
                                               float* __restrict__ dst) {
    __shared__ float s[64][65];
    int tid = threadIdx.x;
#pragma unroll
    for (int rep = 0; rep < 16; ++rep) {
        int idx = rep * 256 + tid;
        s[idx >> 6][idx & 63] = src[idx];
    }
    __syncthreads();
    int n = (blockIdx.x << 2) + (tid >> 6);  // wave-uniform row
    int m = tid & 63;
    float a0 = 0.f, a1 = 0.f, a2 = 0.f, a3 = 0.f;
#pragma unroll
    for (int k = 0; k < 64; k += 4) {
        a0 = fmaf(s[n][k + 0], s[k + 0][m], a0);
        a1 = fmaf(s[n][k + 1], s[k + 1][m], a1);
        a2 = fmaf(s[n][k + 2], s[k + 2][m], a2);
        a3 = fmaf(s[n][k + 3], s[k + 3][m], a3);
    }
    dst[(n << 6) + m] = (a0 + a1) + (a2 + a3);
}

// ---------------- cvt: elementwise f32 -> (hi,lo) bf16 split, opt scale by dt ----------------
__global__ __launch_bounds__(256) void k_cvt(const float* __restrict__ src,
                                             const float* __restrict__ ws,
                                             unsigned short* __restrict__ hi,
                                             unsigned short* __restrict__ lo,
                                             int use_dt) {
    int i = (blockIdx.x * 256 + threadIdx.x) * 4;   // grid covers 65536 elems
    float scale = use_dt ? ws[0] : 1.f;
    float4 v = *reinterpret_cast<const float4*>(&src[i]);
    v.x *= scale; v.y *= scale; v.z *= scale; v.w *= scale;
    ushort4 h, l;
    h.x = bf16_rne(v.x); l.x = bf16_rne(v.x - bf16f(h.x));
    h.y = bf16_rne(v.y); l.y = bf16_rne(v.y - bf16f(h.y));
    h.z = bf16_rne(v.z); l.z = bf16_rne(v.z - bf16f(h.z));
    h.w = bf16_rne(v.w); l.w = bf16_rne(v.w - bf16f(h.w));
    *reinterpret_cast<ushort4*>(&hi[i]) = h;
    *reinterpret_cast<ushort4*>(&lo[i]) = l;
}

// ---------------- GEMM1: bu = u @ (dt*B)^T  (M=65536,K=1024,N=64) ----------------
// Register-prefetch pipeline: loads for tile t+1 issue after tile t's LDS writes,
// landing during MFMA(t) + syncs. B arrives pre-split (no conversion here).
__global__ __launch_bounds__(256) void k_gemm1(const float* __restrict__ u,
                                               const float* __restrict__ ws,
                                               float* __restrict__ bu) {
    __shared__ short a_hi[128][72], a_lo[128][72];
    __shared__ short b_hi[64][72],  b_lo[64][72];
    const unsigned short* bhig = (const unsigned short*)(ws + WS_BHI);
    const unsigned short* blog = (const unsigned short*)(ws + WS_BLO);
    int tid = threadIdx.x;
    int m0 = blockIdx.x * 128;
    int wid = tid >> 6, lane = tid & 63;
    int lr = lane & 15, lg = lane >> 4;
    // staging coords
    int sr = tid >> 4, sc4 = (tid & 15) << 2;        // u: row sr + 16*i, col sc4
    int bn = tid >> 3, bk8 = (tid & 7) << 3;         // B: row bn + 32*j, col bk8

    f32x4 acc[2][4];
#pragma unroll
    for (int i = 0; i < 2; ++i)
#pragma unroll
        for (int j = 0; j < 4; ++j) acc[i][j] = (f32x4)(0.f);

    float4 ra[8];
    ushort8 rbh[2], rbl[2];
    // preload K-tile 0
#pragma unroll
    for (int i = 0; i < 8; ++i)
        ra[i] = *reinterpret_cast<const float4*>(&u[(size_t)(m0 + sr + 16 * i) * DM + sc4]);
#pragma unroll
    for (int j = 0; j < 2; ++j) {
        rbh[j] = *reinterpret_cast<const ushort8*>(&bhig[(size_t)(bn + 32 * j) * DM + bk8]);
        rbl[j] = *reinterpret_cast<const ushort8*>(&blog[(size_t)(bn + 32 * j) * DM + bk8]);
    }

    for (int kt = 0; kt < 16; ++kt) {
        // convert + write LDS (consumes regs of tile kt)
#pragma unroll
        for (int i = 0; i < 8; ++i) {
            float4 v = ra[i];
            ushort4 h, l;
            h.x = bf16_rne(v.x); l.x = bf16_rne(v.x - bf16f(h.x));
            h.y = bf16_rne(v.y); l.y = bf16_rne(v.y - bf16f(h.y));
            h.z = bf16_rne(v.z); l.z = bf16_rne(v.z - bf16f(h.z));
            h.w = bf16_rne(v.w); l.w = bf16_rne(v.w - bf16f(h.w));
            *reinterpret_cast<ushort4*>(&a_hi[sr + 16 * i][sc4]) = h;
            *reinterpret_cast<ushort4*>(&a_lo[sr + 16 * i][sc4]) = l;
        }
#pragma unroll
        for (int j = 0; j < 2; ++j) {
            *reinterpret_cast<ushort8*>(&b_hi[bn + 32 * j][bk8]) = rbh[j];
            *reinterpret_cast<ushort8*>(&b_lo[bn + 32 * j][bk8]) = rbl[j];
        }
        __syncthreads();
        // issue next tile's loads (land during MFMA below)
        if (kt + 1 < 16) {
            int k0n = (kt + 1) * 64;
#pragma unroll
            for (int i = 0; i < 8; ++i)
                ra[i] = *reinterpret_cast<const float4*>(&u[(size_t)(m0 + sr + 16 * i) * DM + k0n + sc4]);
#pragma unroll
            for (int j = 0; j < 2; ++j) {
                rbh[j] = *reinterpret_cast<const ushort8*>(&bhig[(size_t)(bn + 32 * j) * DM + k0n + bk8]);
                rbl[j] = *reinterpret_cast<const ushort8*>(&blog[(size_t)(bn + 32 * j) * DM + k0n + bk8]);
            }
        }
#pragma unroll
        for (int kf = 0; kf < 2; ++kf) {
            int kb = kf * 32 + lg * 8;
            bf16x8 ah[2], al[2];
#pragma unroll
            for (int mf = 0; mf < 2; ++mf) {
                ah[mf] = *reinterpret_cast<bf16x8*>(&a_hi[wid * 32 + mf * 16 + lr][kb]);
                al[mf] = *reinterpret_cast<bf16x8*>(&a_lo[wid * 32 + mf * 16 + lr][kb]);
            }
#pragma unroll
            for (int nf = 0; nf < 4; ++nf) {
                bf16x8 bh = *reinterpret_cast<bf16x8*>(&b_hi[nf * 16 + lr][kb]);
                bf16x8 bl = *reinterpret_cast<bf16x8*>(&b_lo[nf * 16 + lr][kb]);
#pragma unroll
                for (int mf = 0; mf < 2; ++mf) {
                    acc[mf][nf] = __builtin_amdgcn_mfma_f32_16x16x32_bf16(ah[mf], bh, acc[mf][nf], 0, 0, 0);
                    acc[mf][nf] = __builtin_amdgcn_mfma_f32_16x16x32_bf16(ah[mf], bl, acc[mf][nf], 0, 0, 0);
                    acc[mf][nf] = __builtin_amdgcn_mfma_f32_16x16x32_bf16(al[mf], bh, acc[mf][nf], 0, 0, 0);
                }
            }
        }
        __syncthreads();
    }
#pragma unroll
    for (int mf = 0; mf < 2; ++mf)
#pragma unroll
        for (int nf = 0; nf < 4; ++nf)
#pragma unroll
            for (int q = 0; q < 4; ++q) {
                size_t row = (size_t)(m0 + wid * 32 + mf * 16 + lg * 4 + q);
                bu[row * DS + nf * 16 + lr] = acc[mf][nf][q];
            }
}

// ---------------- chunked scan: 2 independent tasks per wave ----------------
template <int PASS>
__global__ __launch_bounds__(256) void k_scan(float* __restrict__ ws) {
    const float* Abar = ws + WS_ABAR;
    float* bu = ws + WS_BU;
    int tid = threadIdx.x;
    int w = tid >> 6, lane = tid & 63;
    int t0 = blockIdx.x * 4 + w;            // 0..511
    int t1 = t0 + 512;                      // 512..1023
    __shared__ float xbuf[4][2][64];

    float a_row[64];
#pragma unroll
    for (int mg = 0; mg < 16; ++mg) {
        float4 v = *reinterpret_cast<const float4*>(&Abar[lane * 64 + mg * 4]);
        a_row[mg * 4 + 0] = v.x; a_row[mg * 4 + 1] = v.y;
        a_row[mg * 4 + 2] = v.z; a_row[mg * 4 + 3] = v.w;
    }
    float x0, x1;
    if (PASS == 0) { x0 = 0.f; x1 = 0.f; }
    else {
        x0 = ws[WS_S + (size_t)t0 * DS + lane];
        x1 = ws[WS_S + (size_t)t1 * DS + lane];
    }
    float* bub0 = bu + ((size_t)(t0 >> 6) * LL + (size_t)(t0 & 63) * LC) * DS;
    float* bub1 = bu + ((size_t)(t1 >> 6) * LL + (size_t)(t1 & 63) * LC) * DS;
    unsigned* bup0 = reinterpret_cast<unsigned*>(bub0);
    unsigned* bup1 = reinterpret_cast<unsigned*>(bub1);
    float v0 = bub0[lane], v1 = bub1[lane];
    for (int t = 0; t < LC; ++t) {
        float n0 = 0.f, n1 = 0.f;
        if (t + 1 < LC) {                    // prefetch next inputs
            n0 = bub0[(t + 1) * DS + lane];
            n1 = bub1[(t + 1) * DS + lane];
        }
        xbuf[w][0][lane] = x0;
        xbuf[w][1][lane] = x1;
        asm volatile("" ::: "memory");
        float p0[4], p1[4];
#pragma unroll
        for (int g = 0; g < 4; ++g) {
            float acc0 = (g == 0) ? v0 : 0.f;
            float acc1 = (g == 0) ? v1 : 0.f;
#pragma unroll
            for (int q = 0; q < 4; ++q) {
                float4 m0v = *reinterpret_cast<float4*>(&xbuf[w][0][g * 16 + q * 4]);
                float4 m1v = *reinterpret_cast<float4*>(&xbuf[w][1][g * 16 + q * 4]);
                float c0 = a_row[g * 16 + q * 4 + 0], c1 = a_row[g * 16 + q * 4 + 1];
                float c2 = a_row[g * 16 + q * 4 + 2], c3 = a_row[g * 16 + q * 4 + 3];
                acc0 = fmaf(c0, m0v.x, acc0); acc1 = fmaf(c0, m1v.x, acc1);
                acc0 = fmaf(c1, m0v.y, acc0); acc1 = fmaf(c1, m1v.y, acc1);
                acc0 = fmaf(c2, m0v.z, acc0); acc1 = fmaf(c2, m1v.z, acc1);
                acc0 = fmaf(c3, m0v.w, acc0); acc1 = fmaf(c3, m1v.w, acc1);
            }
            p0[g] = acc0; p1[g] = acc1;
        }
        asm volatile("" ::: "memory");
        x0 = (p0[0] + p0[1]) + (p0[2] + p0[3]);
        x1 = (p1[0] + p1[1]) + (p1[2] + p1[3]);
        if (PASS == 1) {
            unsigned short h0 = bf16_rne(x0);
            unsigned short l0 = bf16_rne(x0 - bf16f(h0));
            unsigned short h1 = bf16_rne(x1);
            unsigned short l1 = bf16_rne(x1 - bf16f(h1));
            bup0[t * DS + lane] = (unsigned)h0 | ((unsigned)l0 << 16);
            bup1[t * DS + lane] = (unsigned)h1 | ((unsigned)l1 << 16);
        }
        v0 = n0; v1 = n1;
    }
    if (PASS == 0) {
        ws[WS_E + (size_t)t0 * DS + lane] = x0;
        ws[WS_E + (size_t)t1 * DS + lane] = x1;
    }
}

// ---------------- sequential chunk-boundary propagation ----------------
__global__ __launch_bounds__(64) void k_combine(float* __restrict__ ws) {
    const float* Apow = ws + WS_APOW;
    int b = blockIdx.x;
    int lane = threadIdx.x;
    __shared__ float xbuf[64];
    __shared__ float e_lds[NCH][64];         // 16 KB: all E for this batch
    const float* Eb = ws + WS_E + (size_t)b * NCH * DS;
#pragma unroll
    for (int r = 0; r < 16; ++r) {           // 64 thr * 16 float4 = 4096 floats
        int idx = r * 64 + lane;
        int jj = idx >> 4, c4 = (idx & 15) << 2;
        *reinterpret_cast<float4*>(&e_lds[jj][c4]) =
            *reinterpret_cast<const float4*>(&Eb[jj * DS + c4]);
    }
    float p_row[64];
#pragma unroll
    for (int mg = 0; mg < 16; ++mg) {
        float4 v = *reinterpret_cast<const float4*>(&Apow[lane * 64 + mg * 4]);
        p_row[mg * 4 + 0] = v.x; p_row[mg * 4 + 1] = v.y;
        p_row[mg * 4 + 2] = v.z; p_row[mg * 4 + 3] = v.w;
    }
    __syncthreads();
    float x = 0.f;
    for (int jj = 0; jj < NCH; ++jj) {
        size_t task = (size_t)b * NCH + jj;
        ws[WS_S + task * DS + lane] = x;
        float e = e_lds[jj][lane];
        xbuf[lane] = x;
        asm volatile("" ::: "memory");
        float part[4];
#pragma unroll
        for (int g = 0; g < 4; ++g) {
            float acc = (g == 0) ? e : 0.f;
#pragma unroll
            for (int q = 0; q < 4; ++q) {
                float4 xm = *reinterpret_cast<float4*>(&xbuf[g * 16 + q * 4]);
                acc = fmaf(p_row[g * 16 + q * 4 + 0], xm.x, acc);
                acc = fmaf(p_row[g * 16 + q * 4 + 1], xm.y, acc);
                acc = fmaf(p_row[g * 16 + q * 4 + 2], xm.z, acc);
                acc = fmaf(p_row[g * 16 + q * 4 + 3], xm.w, acc);
            }
            part[g] = acc;
        }
        asm volatile("" ::: "memory");
        x = (part[0] + part[1]) + (part[2] + part[3]);
    }
}

// ---------------- GEMM2: y = xs @ C^T + u*D  (M=65536,K=64,N=1024) ----------------
// M-tile 128, N-tile 128. xs arrives packed bf16(hi,lo); C arrives pre-split.
__global__ __launch_bounds__(256) void k_gemm2(const float* __restrict__ u,
                                               const float* __restrict__ Dv,
                                               const float* __restrict__ ws,
                                               float* __restrict__ y) {
    __shared__ __align__(16) char smem[4 * 128 * 72 * 2];   // 73728 B
    short (*a_hi)[72] = (short(*)[72])(smem);
    short (*a_lo)[72] = (short(*)[72])(smem + 18432);
    short (*c_hi)[72] = (short(*)[72])(smem + 36864);
    short (*c_lo)[72] = (short(*)[72])(smem + 55296);
    float (*out_lds)[132] = (float(*)[132])(smem);          // 67584 B, reused

    const unsigned* bup = reinterpret_cast<const unsigned*>(ws + WS_BU);
    const unsigned short* chig = (const unsigned short*)(ws + WS_CHI);
    const unsigned short* clog = (const unsigned short*)(ws + WS_CLO);
    int tid = threadIdx.x;
    int m0 = blockIdx.x * 128;
    int d0 = blockIdx.y * 128;
    int wid = tid >> 6, lane = tid & 63;
    int lr = lane & 15, lg = lane >> 4;

#pragma unroll
    for (int rep = 0; rep < 8; ++rep) {            // stage xs tile 128x64 (packed hi|lo)
        int idx = rep * 256 + tid;
        int r = idx >> 4, c4 = (idx & 15) << 2;
        uint4 v = *reinterpret_cast<const uint4*>(&bup[(size_t)(m0 + r) * DS + c4]);
        ushort4 h, l;
        h.x = (unsigned short)(v.x & 0xFFFF); l.x = (unsigned short)(v.x >> 16);
        h.y = (unsigned short)(v.y & 0xFFFF); l.y = (unsigned short)(v.y >> 16);
        h.z = (unsigned short)(v.z & 0xFFFF); l.z = (unsigned short)(v.z >> 16);
        h.w = (unsigned short)(v.w & 0xFFFF); l.w = (unsigned short)(v.w >> 16);
        *reinterpret_cast<ushort4*>(&a_hi[r][c4]) = h;
        *reinterpret_cast<ushort4*>(&a_lo[r][c4]) = l;
    }
#pragma unroll
    for (int rep = 0; rep < 4; ++rep) {            // stage C^T tile (pre-split) 128x64
        int idx = rep * 256 + tid;
        int dl = idx >> 3, n8 = (idx & 7) << 3;
        *reinterpret_cast<ushort8*>(&c_hi[dl][n8]) =
            *reinterpret_cast<const ushort8*>(&chig[(size_t)(d0 + dl) * DS + n8]);
        *reinterpret_cast<ushort8*>(&c_lo[dl][n8]) =
            *reinterpret_cast<const ushort8*>(&clog[(size_t)(d0 + dl) * DS + n8]);
    }
    __syncthreads();

    f32x4 acc[2][8];
#pragma unroll
    for (int i = 0; i < 2; ++i)
#pragma unroll
        for (int j = 0; j < 8; ++j) acc[i][j] = (f32x4)(0.f);

#pragma unroll
    for (int kf = 0; kf < 2; ++kf) {
        int kb = kf * 32 + lg * 8;
        bf16x8 ah[2], al[2];
#pragma unroll
        for (int mf = 0; mf < 2; ++mf) {
            ah[mf] = *reinterpret_cast<bf16x8*>(&a_hi[wid * 32 + mf * 16 + lr][kb]);
            al[mf] = *reinterpret_cast<bf16x8*>(&a_lo[wid * 32 + mf * 16 + lr][kb]);
        }
#pragma unroll
        for (int nf = 0; nf < 8; ++nf) {
            bf16x8 bh = *reinterpret_cast<bf16x8*>(&c_hi[nf * 16 + lr][kb]);
            bf16x8 bl = *reinterpret_cast<bf16x8*>(&c_lo[nf * 16 + lr][kb]);
#pragma unroll
            for (int mf = 0; mf < 2; ++mf) {
                acc[mf][nf] = __builtin_amdgcn_mfma_f32_16x16x32_bf16(ah[mf], bh, acc[mf][nf], 0, 0, 0);
                acc[mf][nf] = __builtin_amdgcn_mfma_f32_16x16x32_bf16(ah[mf], bl, acc[mf][nf], 0, 0, 0);
                acc[mf][nf] = __builtin_amdgcn_mfma_f32_16x16x32_bf16(al[mf], bh, acc[mf][nf], 0, 0, 0);
            }
        }
    }
    __syncthreads();   // frag reads done; reuse smem as f32 [128][132]
#pragma unroll
    for (int mf = 0; mf < 2; ++mf)
#pragma unroll
        for (int nf = 0; nf < 8; ++nf)
#pragma unroll
            for (int q = 0; q < 4; ++q)
                out_lds[wid * 32 + mf * 16 + lg * 4 + q][nf * 16 + lr] = acc[mf][nf][q];
    __syncthreads();
#pragma unroll
    for (int rep = 0; rep < 16; ++rep) {           // coalesced float4 epilogue
        int idx = rep * 256 + tid;
        int r = idx >> 5, c4 = (idx & 31) << 2;
        float4 a = *reinterpret_cast<float4*>(&out_lds[r][c4]);
        size_t row = (size_t)(m0 + r);
        int c = d0 + c4;
        float4 uv = *reinterpret_cast<const float4*>(&u[row * DM + c]);
        float4 dv = *reinterpret_cast<const float4*>(&Dv[c]);
        float4 o;
        o.x = a.x + uv.x * dv.x;
        o.y = a.y + uv.y * dv.y;
        o.z = a.z + uv.z * dv.z;
        o.w = a.w + uv.w * dv.w;
        *reinterpret_cast<float4*>(&y[row * DM + c]) = o;
    }
}

extern "C" void kernel_launch(void* const* d_in, const int* in_sizes, int n_in,
                              void* d_out, int out_size, void* d_ws, size_t ws_size,
                              hipStream_t stream) {
    (void)in_sizes; (void)n_in; (void)out_size; (void)ws_size;
    const float* u      = (const float*)d_in[0];
    const float* A      = (const float*)d_in[1];
    const float* Bm     = (const float*)d_in[2];
    const float* C      = (const float*)d_in[3];
    const float* Dv     = (const float*)d_in[4];
    const float* log_dt = (const float*)d_in[5];
    float* y  = (float*)d_out;
    float* ws = (float*)d_ws;
    float* bu = ws + WS_BU;
    unsigned short* bhi = (unsigned short*)(ws + WS_BHI);
    unsigned short* blo = (unsigned short*)(ws + WS_BLO);
    unsigned short* chi = (unsigned short*)(ws + WS_CHI);
    unsigned short* clo = (unsigned short*)(ws + WS_CLO);

    k_prep<<<dim3(1), dim3(256), 0, stream>>>(A, log_dt, ws);
    k_cvt<<<dim3(64), dim3(256), 0, stream>>>(Bm, ws, bhi, blo, 1);  // split(dt*B)
    k_cvt<<<dim3(64), dim3(256), 0, stream>>>(C,  ws, chi, clo, 0);  // split(C)
    k_matsq<<<dim3(16), dim3(256), 0, stream>>>(ws + WS_ABAR, ws + WS_TMP);   // A^2
    k_matsq<<<dim3(16), dim3(256), 0, stream>>>(ws + WS_TMP,  ws + WS_APOW);  // A^4
    k_matsq<<<dim3(16), dim3(256), 0, stream>>>(ws + WS_APOW, ws + WS_TMP);   // A^8
    k_matsq<<<dim3(16), dim3(256), 0, stream>>>(ws + WS_TMP,  ws + WS_APOW);  // A^16
    k_matsq<<<dim3(16), dim3(256), 0, stream>>>(ws + WS_APOW, ws + WS_TMP);   // A^32
    k_matsq<<<dim3(16), dim3(256), 0, stream>>>(ws + WS_TMP,  ws + WS_APOW);  // A^64

    k_gemm1<<<dim3(MTOT / 128), dim3(256), 0, stream>>>(u, ws, bu);
    k_scan<0><<<dim3(NTASK / 8), dim3(256), 0, stream>>>(ws);
    k_combine<<<dim3(NB), dim3(64), 0, stream>>>(ws);
    k_scan<1><<<dim3(NTASK / 8), dim3(256), 0, stream>>>(ws);
    k_gemm2<<<dim3(MTOT / 128, DM / 128), dim3(256), 0, stream>>>(u, Dv, ws, y);
}

// Round 6
// 349.639 us; speedup vs baseline: 1.5655x; 1.1333x over previous
//
#include <hip/hip_runtime.h>

// S4 layer: y = C * scan(a_bar, dt*B*u) + u*D
//   prep:     dt = mean(exp(log_dt)); A_bar = I + dt*A
//   cvt:      B_hat = bf16(dt*B), C_hat = bf16(C)  (single bf16; scan-noise dominates)
//   matsq x6: A_pow = A_bar^64
//   gemm1:    bu[m][n] = sum_k u[m][k]*(dt*B)[n][k]   (MFMA bf16, M-tile 64, reg-pipelined)
//   scan<0>:  per-chunk local scan from zero -> chunk end states E  (2 tasks/wave)
//   combine:  S_{j+1} = A_pow * S_j + E_j
//   scan<1>:  re-run recurrence with true initial states; writes xs as bf16
//   gemm2:    y[m][d] = sum_n xs[m][n]*C[d][n] + u[m][d]*D[d]  (MFMA bf16, 128x128 tile)

#define DM   1024
#define DS   64
#define NB   16
#define LL   4096
#define LC   64
#define NCH  (LL / LC)     // 64
#define MTOT (NB * LL)     // 65536
#define NTASK (NB * NCH)   // 1024

// workspace layout in floats
#define WS_ABAR 64
#define WS_APOW (WS_ABAR + 4096)          // 4160
#define WS_TMP  (WS_APOW + 4096)          // 8256
#define WS_E    (WS_TMP + 4096)           // 12352
#define WS_S    (WS_E + NTASK * DS)       // 77888
#define WS_BHI  143424                    // 65536 ushort = 32768 floats
#define WS_CHI  (WS_BHI + 32768)          // 176192
#define WS_XS   (WS_CHI + 32768)          // 208960: 4194304 ushort = 2097152 floats
#define WS_BU   (WS_XS + 2097152)         // 2306112
// total = 2306112 + 4194304 floats ~= 26 MB

typedef __attribute__((ext_vector_type(4))) float f32x4;
typedef __attribute__((ext_vector_type(8))) short bf16x8;
typedef __attribute__((ext_vector_type(8))) unsigned short ushort8;

__device__ inline unsigned short bf16_rne(float f) {
    unsigned u = __builtin_bit_cast(unsigned, f);
    u += 0x7FFFu + ((u >> 16) & 1u);
    return (unsigned short)(u >> 16);
}

// ---------------- prep: dt + A_bar ----------------
__global__ __launch_bounds__(256) void k_prep(const float* __restrict__ A,
                                              const float* __restrict__ log_dt,
                                              float* __restrict__ ws) {
    __shared__ float red[256];
    int tid = threadIdx.x;
    float s = 0.f;
    for (int i = tid; i < DM; i += 256) s += expf(log_dt[i]);
    red[tid] = s;
    __syncthreads();
    for (int off = 128; off > 0; off >>= 1) {
        if (tid < off) red[tid] += red[tid + off];
        __syncthreads();
    }
    float dt = red[0] * (1.f / (float)DM);
    if (tid == 0) ws[0] = dt;
    for (int idx = tid; idx < 4096; idx += 256) {
        int n = idx >> 6, m = idx & 63;
        ws[WS_ABAR + idx] = dt * A[idx] + ((n == m) ? 1.f : 0.f);
    }
}

// ---------------- cvt: B (scaled by dt) and C -> bf16, one launch ----------------
__global__ __launch_bounds__(256) void k_cvt(const float* __restrict__ Bm,
                                             const float* __restrict__ C,
                                             float* __restrict__ ws) {
    int bid = blockIdx.x;
    int isC = bid >> 6;                      // blocks 0..63: B, 64..127: C
    const float* src = isC ? C : Bm;
    unsigned short* dst = (unsigned short*)(ws + (isC ? WS_CHI : WS_BHI));
    float scale = isC ? 1.f : ws[0];
    int i = ((bid & 63) * 256 + threadIdx.x) * 4;
    float4 v = *reinterpret_cast<const float4*>(&src[i]);
    ushort4 h;
    h.x = bf16_rne(v.x * scale);
    h.y = bf16_rne(v.y * scale);
    h.z = bf16_rne(v.z * scale);
    h.w = bf16_rne(v.w * scale);
    *reinterpret_cast<ushort4*>(&dst[i]) = h;
}

// dst = src*src for a 64x64 matrix. grid=16 blocks x 256 thr.
__global__ __launch_bounds__(256) void k_matsq(const float* __restrict__ src,
                                               float* __restrict__ dst) {
    __shared__ float s[64][65];
    int tid = threadIdx.x;
#pragma unroll
    for (int rep = 0; rep < 16; ++rep) {
        int idx = rep * 256 + tid;
        s[idx >> 6][idx & 63] = src[idx];
    }
    __syncthreads();
    int n = (blockIdx.x << 2) + (tid >> 6);  // wave-uniform row
    int m = tid & 63;
    float a0 = 0.f, a1 = 0.f, a2 = 0.f, a3 = 0.f;
#pragma unroll
    for (int k = 0; k < 64; k += 4) {
        a0 = fmaf(s[n][k + 0], s[k + 0][m], a0);
        a1 = fmaf(s[n][k + 1], s[k + 1][m], a1);
        a2 = fmaf(s[n][k + 2], s[k + 2][m], a2);
        a3 = fmaf(s[n][k + 3], s[k + 3][m], a3);
    }
    dst[(n << 6) + m] = (a0 + a1) + (a2 + a3);
}

// ---------------- GEMM1: bu = u @ (dt*B)^T  (M=65536,K=1024,N=64) ----------------
// M-tile 64 (grid 1024 = 4 blocks/CU), single bf16, register-prefetch pipeline.
__global__ __launch_bounds__(256, 4) void k_gemm1(const float* __restrict__ u,
                                                  const float* __restrict__ ws,
                                                  float* __restrict__ bu) {
    __shared__ short a_t[64][72];    // 9216 B
    __shared__ short b_t[64][72];    // 9216 B
    const unsigned short* bhig = (const unsigned short*)(ws + WS_BHI);
    int tid = threadIdx.x;
    int m0 = blockIdx.x * 64;
    int wid = tid >> 6, lane = tid & 63;
    int lr = lane & 15, lg = lane >> 4;
    // staging coords: u rows sr+32*i, 8 cols at sc8; B rows bn+32*j, 8 cols at bk8
    int sr = tid >> 3, sc8 = (tid & 7) << 3;
    int bn = tid >> 3, bk8 = (tid & 7) << 3;

    f32x4 acc[4];
#pragma unroll
    for (int j = 0; j < 4; ++j) acc[j] = (f32x4)(0.f);

    float4 ra[2][2];                 // [row group i][col half]
    ushort8 rb[2];
    // preload K-tile 0
#pragma unroll
    for (int i = 0; i < 2; ++i) {
        ra[i][0] = *reinterpret_cast<const float4*>(&u[(size_t)(m0 + sr + 32 * i) * DM + sc8]);
        ra[i][1] = *reinterpret_cast<const float4*>(&u[(size_t)(m0 + sr + 32 * i) * DM + sc8 + 4]);
    }
#pragma unroll
    for (int j = 0; j < 2; ++j)
        rb[j] = *reinterpret_cast<const ushort8*>(&bhig[(size_t)(bn + 32 * j) * DM + bk8]);

    for (int kt = 0; kt < 16; ++kt) {
        // convert + b128 LDS writes (conflict-free quads: (row+col8)%8 uniform)
#pragma unroll
        for (int i = 0; i < 2; ++i) {
            ushort8 h;
            h[0] = bf16_rne(ra[i][0].x); h[1] = bf16_rne(ra[i][0].y);
            h[2] = bf16_rne(ra[i][0].z); h[3] = bf16_rne(ra[i][0].w);
            h[4] = bf16_rne(ra[i][1].x); h[5] = bf16_rne(ra[i][1].y);
            h[6] = bf16_rne(ra[i][1].z); h[7] = bf16_rne(ra[i][1].w);
            *reinterpret_cast<ushort8*>(&a_t[sr + 32 * i][sc8]) = h;
        }
#pragma unroll
        for (int j = 0; j < 2; ++j)
            *reinterpret_cast<ushort8*>(&b_t[bn + 32 * j][bk8]) = rb[j];
        __syncthreads();
        // issue next tile's loads (land during MFMA below)
        if (kt + 1 < 16) {
            int k0n = (kt + 1) * 64;
#pragma unroll
            for (int i = 0; i < 2; ++i) {
                ra[i][0] = *reinterpret_cast<const float4*>(&u[(size_t)(m0 + sr + 32 * i) * DM + k0n + sc8]);
                ra[i][1] = *reinterpret_cast<const float4*>(&u[(size_t)(m0 + sr + 32 * i) * DM + k0n + sc8 + 4]);
            }
#pragma unroll
            for (int j = 0; j < 2; ++j)
                rb[j] = *reinterpret_cast<const ushort8*>(&bhig[(size_t)(bn + 32 * j) * DM + k0n + bk8]);
        }
#pragma unroll
        for (int kf = 0; kf < 2; ++kf) {
            int kb = kf * 32 + lg * 8;
            bf16x8 af = *reinterpret_cast<bf16x8*>(&a_t[wid * 16 + lr][kb]);
#pragma unroll
            for (int nf = 0; nf < 4; ++nf) {
                bf16x8 bf_ = *reinterpret_cast<bf16x8*>(&b_t[nf * 16 + lr][kb]);
                acc[nf] = __builtin_amdgcn_mfma_f32_16x16x32_bf16(af, bf_, acc[nf], 0, 0, 0);
            }
        }
        __syncthreads();
    }
#pragma unroll
    for (int nf = 0; nf < 4; ++nf)
#pragma unroll
        for (int q = 0; q < 4; ++q) {
            size_t row = (size_t)(m0 + wid * 16 + lg * 4 + q);
            bu[row * DS + nf * 16 + lr] = acc[nf][q];
        }
}

// ---------------- chunked scan: 2 independent tasks per wave ----------------
template <int PASS>
__global__ __launch_bounds__(256) void k_scan(float* __restrict__ ws) {
    const float* Abar = ws + WS_ABAR;
    float* bu = ws + WS_BU;
    unsigned short* xs = (unsigned short*)(ws + WS_XS);
    int tid = threadIdx.x;
    int w = tid >> 6, lane = tid & 63;
    int t0 = blockIdx.x * 4 + w;            // 0..511
    int t1 = t0 + 512;                      // 512..1023
    __shared__ float xbuf[4][2][64];

    float a_row[64];
#pragma unroll
    for (int mg = 0; mg < 16; ++mg) {
        float4 v = *reinterpret_cast<const float4*>(&Abar[lane * 64 + mg * 4]);
        a_row[mg * 4 + 0] = v.x; a_row[mg * 4 + 1] = v.y;
        a_row[mg * 4 + 2] = v.z; a_row[mg * 4 + 3] = v.w;
    }
    float x0, x1;
    if (PASS == 0) { x0 = 0.f; x1 = 0.f; }
    else {
        x0 = ws[WS_S + (size_t)t0 * DS + lane];
        x1 = ws[WS_S + (size_t)t1 * DS + lane];
    }
    size_t r0 = (size_t)(t0 >> 6) * LL + (size_t)(t0 & 63) * LC;
    size_t r1 = (size_t)(t1 >> 6) * LL + (size_t)(t1 & 63) * LC;
    float* bub0 = bu + r0 * DS;
    float* bub1 = bu + r1 * DS;
    unsigned short* xp0 = xs + r0 * DS;
    unsigned short* xp1 = xs + r1 * DS;
    float v0 = bub0[lane], v1 = bub1[lane];
    for (int t = 0; t < LC; ++t) {
        float n0 = 0.f, n1 = 0.f;
        if (t + 1 < LC) {                    // prefetch next inputs
            n0 = bub0[(t + 1) * DS + lane];
            n1 = bub1[(t + 1) * DS + lane];
        }
        xbuf[w][0][lane] = x0;
        xbuf[w][1][lane] = x1;
        asm volatile("" ::: "memory");
        float p0[4], p1[4];
#pragma unroll
        for (int g = 0; g < 4; ++g) {
            float acc0 = (g == 0) ? v0 : 0.f;
            float acc1 = (g == 0) ? v1 : 0.f;
#pragma unroll
            for (int q = 0; q < 4; ++q) {
                float4 m0v = *reinterpret_cast<float4*>(&xbuf[w][0][g * 16 + q * 4]);
                float4 m1v = *reinterpret_cast<float4*>(&xbuf[w][1][g * 16 + q * 4]);
                float c0 = a_row[g * 16 + q * 4 + 0], c1 = a_row[g * 16 + q * 4 + 1];
                float c2 = a_row[g * 16 + q * 4 + 2], c3 = a_row[g * 16 + q * 4 + 3];
                acc0 = fmaf(c0, m0v.x, acc0); acc1 = fmaf(c0, m1v.x, acc1);
                acc0 = fmaf(c1, m0v.y, acc0); acc1 = fmaf(c1, m1v.y, acc1);
                acc0 = fmaf(c2, m0v.z, acc0); acc1 = fmaf(c2, m1v.z, acc1);
                acc0 = fmaf(c3, m0v.w, acc0); acc1 = fmaf(c3, m1v.w, acc1);
            }
            p0[g] = acc0; p1[g] = acc1;
        }
        asm volatile("" ::: "memory");
        x0 = (p0[0] + p0[1]) + (p0[2] + p0[3]);
        x1 = (p1[0] + p1[1]) + (p1[2] + p1[3]);
        if (PASS == 1) {
            xp0[t * DS + lane] = bf16_rne(x0);
            xp1[t * DS + lane] = bf16_rne(x1);
        }
        v0 = n0; v1 = n1;
    }
    if (PASS == 0) {
        ws[WS_E + (size_t)t0 * DS + lane] = x0;
        ws[WS_E + (size_t)t1 * DS + lane] = x1;
    }
}

// ---------------- sequential chunk-boundary propagation ----------------
__global__ __launch_bounds__(64) void k_combine(float* __restrict__ ws) {
    const float* Apow = ws + WS_APOW;
    int b = blockIdx.x;
    int lane = threadIdx.x;
    __shared__ float xbuf[64];
    __shared__ float e_lds[NCH][64];         // 16 KB: all E for this batch
    const float* Eb = ws + WS_E + (size_t)b * NCH * DS;
#pragma unroll
    for (int r = 0; r < 16; ++r) {
        int idx = r * 64 + lane;
        int jj = idx >> 4, c4 = (idx & 15) << 2;
        *reinterpret_cast<float4*>(&e_lds[jj][c4]) =
            *reinterpret_cast<const float4*>(&Eb[jj * DS + c4]);
    }
    float p_row[64];
#pragma unroll
    for (int mg = 0; mg < 16; ++mg) {
        float4 v = *reinterpret_cast<const float4*>(&Apow[lane * 64 + mg * 4]);
        p_row[mg * 4 + 0] = v.x; p_row[mg * 4 + 1] = v.y;
        p_row[mg * 4 + 2] = v.z; p_row[mg * 4 + 3] = v.w;
    }
    __syncthreads();
    float x = 0.f;
    for (int jj = 0; jj < NCH; ++jj) {
        size_t task = (size_t)b * NCH + jj;
        ws[WS_S + task * DS + lane] = x;
        float e = e_lds[jj][lane];
        xbuf[lane] = x;
        asm volatile("" ::: "memory");
        float part[4];
#pragma unroll
        for (int g = 0; g < 4; ++g) {
            float acc = (g == 0) ? e : 0.f;
#pragma unroll
            for (int q = 0; q < 4; ++q) {
                float4 xm = *reinterpret_cast<float4*>(&xbuf[g * 16 + q * 4]);
                acc = fmaf(p_row[g * 16 + q * 4 + 0], xm.x, acc);
                acc = fmaf(p_row[g * 16 + q * 4 + 1], xm.y, acc);
                acc = fmaf(p_row[g * 16 + q * 4 + 2], xm.z, acc);
                acc = fmaf(p_row[g * 16 + q * 4 + 3], xm.w, acc);
            }
            part[g] = acc;
        }
        asm volatile("" ::: "memory");
        x = (part[0] + part[1]) + (part[2] + part[3]);
    }
}

// ---------------- GEMM2: y = xs @ C^T + u*D  (M=65536,K=64,N=1024) ----------------
// M-tile 128, N-tile 128, single bf16, 36.8 KB LDS (epilogue reuses tiles in 2 halves).
__global__ __launch_bounds__(256, 4) void k_gemm2(const float* __restrict__ u,
                                                  const float* __restrict__ Dv,
                                                  const float* __restrict__ ws,
                                                  float* __restrict__ y) {
    __shared__ __align__(16) char smem[2 * 128 * 72 * 2];   // 36864 B
    short (*a_t)[72] = (short(*)[72])(smem);
    short (*c_t)[72] = (short(*)[72])(smem + 18432);
    float (*out_lds)[132] = (float(*)[132])(smem);          // 33792 B reused per half

    const unsigned short* xsb = (const unsigned short*)(ws + WS_XS);
    const unsigned short* chig = (const unsigned short*)(ws + WS_CHI);
    int tid = threadIdx.x;
    int m0 = blockIdx.x * 128;
    int d0 = blockIdx.y * 128;
    int wid = tid >> 6, lane = tid & 63;
    int lr = lane & 15, lg = lane >> 4;

#pragma unroll
    for (int rep = 0; rep < 4; ++rep) {            // stage xs tile 128x64 bf16
        int idx = rep * 256 + tid;
        int r = idx >> 3, k8 = (idx & 7) << 3;
        *reinterpret_cast<ushort8*>(&a_t[r][k8]) =
            *reinterpret_cast<const ushort8*>(&xsb[(size_t)(m0 + r) * DS + k8]);
    }
#pragma unroll
    for (int rep = 0; rep < 4; ++rep) {            // stage C tile 128x64 bf16
        int idx = rep * 256 + tid;
        int dl = idx >> 3, n8 = (idx & 7) << 3;
        *reinterpret_cast<ushort8*>(&c_t[dl][n8]) =
            *reinterpret_cast<const ushort8*>(&chig[(size_t)(d0 + dl) * DS + n8]);
    }
    __syncthreads();

    f32x4 acc[2][8];
#pragma unroll
    for (int i = 0; i < 2; ++i)
#pragma unroll
        for (int j = 0; j < 8; ++j) acc[i][j] = (f32x4)(0.f);

#pragma unroll
    for (int kf = 0; kf < 2; ++kf) {
        int kb = kf * 32 + lg * 8;
        bf16x8 ah0 = *reinterpret_cast<bf16x8*>(&a_t[wid * 32 + lr][kb]);
        bf16x8 ah1 = *reinterpret_cast<bf16x8*>(&a_t[wid * 32 + 16 + lr][kb]);
#pragma unroll
        for (int nf = 0; nf < 8; ++nf) {
            bf16x8 cb = *reinterpret_cast<bf16x8*>(&c_t[nf * 16 + lr][kb]);
            acc[0][nf] = __builtin_amdgcn_mfma_f32_16x16x32_bf16(ah0, cb, acc[0][nf], 0, 0, 0);
            acc[1][nf] = __builtin_amdgcn_mfma_f32_16x16x32_bf16(ah1, cb, acc[1][nf], 0, 0, 0);
        }
    }
    __syncthreads();   // all fragment reads done; smem now reusable

    // epilogue in two 64-row halves through out_lds
#pragma unroll
    for (int h = 0; h < 2; ++h) {
        if ((wid >> 1) == h) {
            int rbase = (wid & 1) * 32;
#pragma unroll
            for (int mf = 0; mf < 2; ++mf)
#pragma unroll
                for (int nf = 0; nf < 8; ++nf)
#pragma unroll
                    for (int q = 0; q < 4; ++q)
                        out_lds[rbase + mf * 16 + lg * 4 + q][nf * 16 + lr] = acc[mf][nf][q];
        }
        __syncthreads();
#pragma unroll
        for (int rep = 0; rep < 8; ++rep) {        // coalesced float4 stores
            int idx = rep * 256 + tid;
            int r = idx >> 5, c4 = (idx & 31) << 2;
            float4 a = *reinterpret_cast<float4*>(&out_lds[r][c4]);
            size_t row = (size_t)(m0 + h * 64 + r);
            int c = d0 + c4;
            float4 uv = *reinterpret_cast<const float4*>(&u[row * DM + c]);
            float4 dv = *reinterpret_cast<const float4*>(&Dv[c]);
            float4 o;
            o.x = a.x + uv.x * dv.x;
            o.y = a.y + uv.y * dv.y;
            o.z = a.z + uv.z * dv.z;
            o.w = a.w + uv.w * dv.w;
            *reinterpret_cast<float4*>(&y[row * DM + c]) = o;
        }
        __syncthreads();
    }
}

extern "C" void kernel_launch(void* const* d_in, const int* in_sizes, int n_in,
                              void* d_out, int out_size, void* d_ws, size_t ws_size,
                              hipStream_t stream) {
    (void)in_sizes; (void)n_in; (void)out_size; (void)ws_size;
    const float* u      = (const float*)d_in[0];
    const float* A      = (const float*)d_in[1];
    const float* Bm     = (const float*)d_in[2];
    const float* C      = (const float*)d_in[3];
    const float* Dv     = (const float*)d_in[4];
    const float* log_dt = (const float*)d_in[5];
    float* y  = (float*)d_out;
    float* ws = (float*)d_ws;
    float* bu = ws + WS_BU;

    k_prep<<<dim3(1), dim3(256), 0, stream>>>(A, log_dt, ws);
    k_cvt<<<dim3(128), dim3(256), 0, stream>>>(Bm, C, ws);
    k_matsq<<<dim3(16), dim3(256), 0, stream>>>(ws + WS_ABAR, ws + WS_TMP);   // A^2
    k_matsq<<<dim3(16), dim3(256), 0, stream>>>(ws + WS_TMP,  ws + WS_APOW);  // A^4
    k_matsq<<<dim3(16), dim3(256), 0, stream>>>(ws + WS_APOW, ws + WS_TMP);   // A^8
    k_matsq<<<dim3(16), dim3(256), 0, stream>>>(ws + WS_TMP,  ws + WS_APOW);  // A^16
    k_matsq<<<dim3(16), dim3(256), 0, stream>>>(ws + WS_APOW, ws + WS_TMP);   // A^32
    k_matsq<<<dim3(16), dim3(256), 0, stream>>>(ws + WS_TMP,  ws + WS_APOW);  // A^64

    k_gemm1<<<dim3(MTOT / 64), dim3(256), 0, stream>>>(u, ws, bu);
    k_scan<0><<<dim3(NTASK / 8), dim3(256), 0, stream>>>(ws);
    k_combine<<<dim3(NB), dim3(64), 0, stream>>>(ws);
    k_scan<1><<<dim3(NTASK / 8), dim3(256), 0, stream>>>(ws);
    k_gemm2<<<dim3(MTOT / 128, DM / 128), dim3(256), 0, stream>>>(u, Dv, ws, y);
}